// Round 12
// baseline (181.024 us; speedup 1.0000x reference)
//
#include <hip/hip_runtime.h>
#include <math.h>

#define B_   128
#define R_   1152
#define RS_  64
#define RCH_ 18            // R_/RS_
#define NBINS 72           // 1152/16 colsum bins

// ws float offsets
#define WS_SP   0          // RS_*32768 = 2097152
#define WS_V    2097152    // 32768
#define WS_BLOG 2129920    // 18432
#define WS_CTRL 2148352    // 2432 floats: cs0 @+0 (72*16), cs1 @+1280
#define WS_WT   2150784    // 2359296 (Wt4[r*512 + d*64 + co4])

__device__ __forceinline__ float squashf(float s) {
    return s * fabsf(s) / (1.0f + s * s);
}

// ---------- G: sp[rs][b][co] = sum_{r in chunk,i} x[b,r,i]*cw[r,c]*W[r,co,i]
// grid dim3(16 bt, 64 rs) x 256 — R8's proven body and hot loop.
// IT==0 absorbs wtrans with COALESCED raw-W reads: per rr the block loads the
// 8KB W row with 2 float4/thread (full sector use — R10's per-lane-contiguous
// read was the 8x over-fetch failure), pitch-65 LDS transpose, double-buffered
// (1 barrier/rr, WAR-safe by parity). bt==0 emits Wt for later dispatches;
// (bt==2,rs==0) zeroes ctrl. No new synchronization (R7/R9 lessons).
// IT>=1: reads Wt coalesced; cw = exp(blog)*1/colsum from 72x16 bins.
template <int IT>
__global__ __launch_bounds__(256) void gemm_s_k(const float* __restrict__ x,
                                                const float* __restrict__ W,
                                                float* __restrict__ wt,
                                                const float* __restrict__ blog,
                                                const float* __restrict__ colbins,
                                                float* __restrict__ sp,
                                                float* __restrict__ ctrl) {
    const int bt  = blockIdx.x;           // 0..15 (8 b each)
    const int rs  = blockIdx.y;
    const int t   = threadIdx.x;
    const int co4 = t & 63;
    const int b4  = t >> 6;               // 0..3 (2 b each)
    const int c   = co4 >> 2;
    const int r0  = rs * RCH_;

    __shared__ float4 xl4[288];           // 8 b x 18 r x 2 f4 = 4.6 KB
    __shared__ float4 wsh[2][520];        // pitch-65 W transpose dbuf (16.6 KB)
    __shared__ float  cwl[RCH_ * 16];
    __shared__ float  colinv_sh[16];
    __shared__ float  psum[256];

    const float4* __restrict__ X4  = (const float4*)x;
    const float4* __restrict__ W4  = (const float4*)W;
    float4* __restrict__ Wt4 = (float4*)wt;

    // stage x tile: 8 b x 18 r x 2 f4
    #pragma unroll
    for (int k = 0; k < 2; ++k) {
        const int u = t + k * 256;
        if (u < 288) {
            const int bl = u / 36, rem = u % 36;
            xl4[u] = X4[((bt * 8 + bl) * R_ + r0) * 2 + rem];
        }
    }

    if (IT == 0) {
        if (bt == 2 && rs == 0) {
            for (int u = t; u < 2432; u += 256) ctrl[u] = 0.0f;
        }
        // prologue: stage W row r0 into buf 0 (coalesced, 2 f4/thread)
        const float4* wrow = W4 + ((size_t)r0 << 9);
        wsh[0][(t & 7) * 65 + (t >> 3)] = wrow[t];
        const int u2 = t + 256;
        wsh[0][(u2 & 7) * 65 + (u2 >> 3)] = wrow[u2];
    } else {
        // prepass: colinv from bins (16 j-lanes x 16 cc), then cwl rows
        const int cc = t & 15, jb = t >> 4;
        float sm = 0.f;
        for (int j = jb; j < NBINS; j += 16) sm += colbins[j * 16 + cc];
        psum[t] = sm;
        __syncthreads();
        if (t < 16) {
            float tot = 0.f;
            #pragma unroll
            for (int k2 = 0; k2 < 16; ++k2) tot += psum[k2 * 16 + t];
            colinv_sh[t] = 1.0f / tot;
        }
        __syncthreads();
        for (int u2 = t; u2 < RCH_ * 16; u2 += 256) {
            const int rl = u2 >> 4, c2 = u2 & 15;
            cwl[u2] = __expf(blog[(r0 + rl) * 16 + c2]) * colinv_sh[c2];
        }
    }
    __syncthreads();

    float acc[2][4];
    #pragma unroll
    for (int j = 0; j < 2; ++j)
        #pragma unroll
        for (int q = 0; q < 4; ++q) acc[j][q] = 0.f;

    #pragma unroll 3
    for (int rr = 0; rr < RCH_; ++rr) {
        const float cwv = (IT == 0) ? (1.0f / (float)R_) : cwl[rr * 16 + c];
        float4 w0, w1, w2, w3, w4, w5, w6, w7;
        if (IT == 0) {
            const int p = rr & 1;
            // prefetch next row into regs (coalesced) while buf p is consumed
            float4 pf0, pf1;
            const bool pf = (rr < RCH_ - 1);
            if (pf) {
                const float4* wrow = W4 + ((size_t)(r0 + rr + 1) << 9);
                pf0 = wrow[t];
                pf1 = wrow[t + 256];
            }
            // fragments from LDS (bank-spread by pitch-65)
            w0 = wsh[p][0 * 65 + co4]; w1 = wsh[p][1 * 65 + co4];
            w2 = wsh[p][2 * 65 + co4]; w3 = wsh[p][3 * 65 + co4];
            w4 = wsh[p][4 * 65 + co4]; w5 = wsh[p][5 * 65 + co4];
            w6 = wsh[p][6 * 65 + co4]; w7 = wsh[p][7 * 65 + co4];
            if (bt == 0) {                 // emit Wt for gemm1/2 and a_k
                float4* wo = Wt4 + ((size_t)(r0 + rr) << 9) + co4;
                wo[  0] = w0; wo[ 64] = w1; wo[128] = w2; wo[192] = w3;
                wo[256] = w4; wo[320] = w5; wo[384] = w6; wo[448] = w7;
            }
            if (pf) {                      // write-behind into the other buffer
                wsh[p ^ 1][(t & 7) * 65 + (t >> 3)] = pf0;
                const int u2 = t + 256;
                wsh[p ^ 1][(u2 & 7) * 65 + (u2 >> 3)] = pf1;
                __syncthreads();           // stores visible before next read
            }
        } else {
            const float4* wp = Wt4 + ((size_t)(r0 + rr) << 9) + co4;  // 16B lane-stride
            w0 = wp[  0]; w1 = wp[ 64]; w2 = wp[128]; w3 = wp[192];
            w4 = wp[256]; w5 = wp[320]; w6 = wp[384]; w7 = wp[448];
        }
        #pragma unroll
        for (int j = 0; j < 2; ++j) {
            const float4 xa = xl4[(b4 * 2 + j) * 36 + rr * 2];
            const float4 xb = xl4[(b4 * 2 + j) * 36 + rr * 2 + 1];
            const float d0 = w0.x*xa.x + w0.y*xa.y + w0.z*xa.z + w0.w*xa.w
                           + w1.x*xb.x + w1.y*xb.y + w1.z*xb.z + w1.w*xb.w;
            const float d1 = w2.x*xa.x + w2.y*xa.y + w2.z*xa.z + w2.w*xa.w
                           + w3.x*xb.x + w3.y*xb.y + w3.z*xb.z + w3.w*xb.w;
            const float d2 = w4.x*xa.x + w4.y*xa.y + w4.z*xa.z + w4.w*xa.w
                           + w5.x*xb.x + w5.y*xb.y + w5.z*xb.z + w5.w*xb.w;
            const float d3 = w6.x*xa.x + w6.y*xa.y + w6.z*xa.z + w6.w*xa.w
                           + w7.x*xb.x + w7.y*xb.y + w7.z*xb.z + w7.w*xb.w;
            acc[j][0] = fmaf(cwv, d0, acc[j][0]);
            acc[j][1] = fmaf(cwv, d1, acc[j][1]);
            acc[j][2] = fmaf(cwv, d2, acc[j][2]);
            acc[j][3] = fmaf(cwv, d3, acc[j][3]);
        }
    }

    float4* sp4 = (float4*)sp;
    #pragma unroll
    for (int j = 0; j < 2; ++j) {
        const int b = bt * 8 + b4 * 2 + j;
        float4 o4; o4.x = acc[j][0]; o4.y = acc[j][1]; o4.z = acc[j][2]; o4.w = acc[j][3];
        sp4[(rs * B_ + b) * 64 + co4] = o4;
    }
}

// ---------- R: v[b,co] = squash(sum_k sp[k][b][co]); grid 256 x 512 (R8-identical)
__global__ __launch_bounds__(512) void reduce_squash_k(const float* __restrict__ sp,
                                                       float* __restrict__ outv) {
    const int t   = threadIdx.x;
    const int li  = t & 127;
    const int kq  = t >> 7;               // 0..3 (16 slices each)
    const int idx = blockIdx.x * 128 + li;
    const float* p = sp + (size_t)kq * 16 * 32768 + idx;
    float a0 = 0.f, a1 = 0.f, a2 = 0.f, a3 = 0.f;
    #pragma unroll
    for (int k = 0; k < 16; k += 4) {
        a0 += p[(k + 0) * 32768];
        a1 += p[(k + 1) * 32768];
        a2 += p[(k + 2) * 32768];
        a3 += p[(k + 3) * 32768];
    }
    __shared__ float red[512];
    red[t] = (a0 + a1) + (a2 + a3);
    __syncthreads();
    if (t < 128) {
        const float s = (red[t] + red[t + 128]) + (red[t + 256] + red[t + 384]);
        outv[idx] = squashf(s);
    }
}

// ---------- A: blog[r,c] (+)= (1/B) sum_{b,o} u_hat[b,r,co]*v[b,co] ----------
// R8-identical (best-run version): grid 1152 x 256, 1 r/block, 4 waves =
// batch quarters; launch_bounds(256,2) keeps y[8][4] in registers;
// 72x16 colsum bins (16-deep atomic chains).
template <bool FIRST>
__global__ __launch_bounds__(256, 2) void a_k(const float* __restrict__ x,
                                              const float* __restrict__ wt,
                                              const float* __restrict__ v,
                                              float* __restrict__ blog,
                                              float* __restrict__ colbins) {
    const int r = blockIdx.x;
    const int t = threadIdx.x;
    const int w = t >> 6, lane = t & 63;
    const int co4 = lane, c = lane >> 2;

    __shared__ float4 xl[256];            // 128 b x 2 f4 = 4 KB
    __shared__ float  red[64];
    const float4* __restrict__ X4  = (const float4*)x;
    const float4* __restrict__ V4  = (const float4*)v;
    const float4* __restrict__ Wt4 = (const float4*)wt;

    xl[t] = X4[((t >> 1) * R_ + r) * 2 + (t & 1)];
    __syncthreads();

    float y[8][4];
    #pragma unroll
    for (int i = 0; i < 8; ++i)
        #pragma unroll
        for (int q = 0; q < 4; ++q) y[i][q] = 0.f;

    const int b0 = w * 32;
    #pragma unroll 4
    for (int bb = 0; bb < 32; ++bb) {
        const int b = b0 + bb;
        const float4 xa = xl[b * 2];
        const float4 xb = xl[b * 2 + 1];
        const float4 vv = V4[b * 64 + co4];
        y[0][0] = fmaf(xa.x, vv.x, y[0][0]); y[0][1] = fmaf(xa.x, vv.y, y[0][1]);
        y[0][2] = fmaf(xa.x, vv.z, y[0][2]); y[0][3] = fmaf(xa.x, vv.w, y[0][3]);
        y[1][0] = fmaf(xa.y, vv.x, y[1][0]); y[1][1] = fmaf(xa.y, vv.y, y[1][1]);
        y[1][2] = fmaf(xa.y, vv.z, y[1][2]); y[1][3] = fmaf(xa.y, vv.w, y[1][3]);
        y[2][0] = fmaf(xa.z, vv.x, y[2][0]); y[2][1] = fmaf(xa.z, vv.y, y[2][1]);
        y[2][2] = fmaf(xa.z, vv.z, y[2][2]); y[2][3] = fmaf(xa.z, vv.w, y[2][3]);
        y[3][0] = fmaf(xa.w, vv.x, y[3][0]); y[3][1] = fmaf(xa.w, vv.y, y[3][1]);
        y[3][2] = fmaf(xa.w, vv.z, y[3][2]); y[3][3] = fmaf(xa.w, vv.w, y[3][3]);
        y[4][0] = fmaf(xb.x, vv.x, y[4][0]); y[4][1] = fmaf(xb.x, vv.y, y[4][1]);
        y[4][2] = fmaf(xb.x, vv.z, y[4][2]); y[4][3] = fmaf(xb.x, vv.w, y[4][3]);
        y[5][0] = fmaf(xb.y, vv.x, y[5][0]); y[5][1] = fmaf(xb.y, vv.y, y[5][1]);
        y[5][2] = fmaf(xb.y, vv.z, y[5][2]); y[5][3] = fmaf(xb.y, vv.w, y[5][3]);
        y[6][0] = fmaf(xb.z, vv.x, y[6][0]); y[6][1] = fmaf(xb.z, vv.y, y[6][1]);
        y[6][2] = fmaf(xb.z, vv.z, y[6][2]); y[6][3] = fmaf(xb.z, vv.w, y[6][3]);
        y[7][0] = fmaf(xb.w, vv.x, y[7][0]); y[7][1] = fmaf(xb.w, vv.y, y[7][1]);
        y[7][2] = fmaf(xb.w, vv.z, y[7][2]); y[7][3] = fmaf(xb.w, vv.w, y[7][3]);
    }

    const float4* wp = Wt4 + ((size_t)r << 9) + co4;
    float part = 0.f;
    #pragma unroll
    for (int q = 0; q < 4; ++q) {
        const float4 w0 = wp[(2 * q) * 64];
        const float4 w1 = wp[(2 * q + 1) * 64];
        part += w0.x*y[0][q] + w0.y*y[1][q] + w0.z*y[2][q] + w0.w*y[3][q]
              + w1.x*y[4][q] + w1.y*y[5][q] + w1.z*y[6][q] + w1.w*y[7][q];
    }
    part += __shfl_xor(part, 1);
    part += __shfl_xor(part, 2);
    if ((lane & 3) == 0) red[w * 16 + c] = part;
    __syncthreads();
    if (t < 16) {
        const float val = ((red[t] + red[16 + t]) + (red[32 + t] + red[48 + t]))
                          * (1.0f / (float)B_);
        const int idx = r * 16 + t;
        const float nv = FIRST ? val : (blog[idx] + val);
        blog[idx] = nv;
        atomicAdd(&colbins[(r >> 4) * 16 + t], __expf(nv));  // 16-deep chains
    }
}

extern "C" void kernel_launch(void* const* d_in, const int* in_sizes, int n_in,
                              void* d_out, int out_size, void* d_ws, size_t ws_size,
                              hipStream_t stream) {
    const float* x = (const float*)d_in[0];   // [128,1152,8]
    const float* W = (const float*)d_in[1];   // [1,1152,16,16,8]
    float* out = (float*)d_out;               // [128,16,16]
    float* ws  = (float*)d_ws;                // ~18 MB used

    float* sp   = ws + WS_SP;
    float* v    = ws + WS_V;
    float* blog = ws + WS_BLOG;
    float* ctrl = ws + WS_CTRL;
    float* wt   = ws + WS_WT;

    float* cs0 = ctrl;                        // 72x16 bins
    float* cs1 = ctrl + 1280;                 // 72x16 bins

    // iter 0 (softmax(0) == 1/R): gemm0 absorbs wtrans (LDS-transposed raw W,
    // Wt emission, ctrl zero) — 8 dispatches total
    gemm_s_k<0><<<dim3(16, RS_), 256, 0, stream>>>(x, W, wt, nullptr, nullptr, sp, ctrl);
    reduce_squash_k<<<256, 512, 0, stream>>>(sp, v);
    a_k<true ><<<R_, 256, 0, stream>>>(x, wt, v, blog, cs0);

    // iter 1
    gemm_s_k<1><<<dim3(16, RS_), 256, 0, stream>>>(x, W, wt, blog, cs0, sp, ctrl);
    reduce_squash_k<<<256, 512, 0, stream>>>(sp, v);
    a_k<false><<<R_, 256, 0, stream>>>(x, wt, v, blog, cs1);

    // iter 2
    gemm_s_k<1><<<dim3(16, RS_), 256, 0, stream>>>(x, W, wt, blog, cs1, sp, ctrl);
    reduce_squash_k<<<256, 512, 0, stream>>>(sp, out);
}

// Round 13
// 168.580 us; speedup vs baseline: 1.0738x; 1.0738x over previous
//
#include <hip/hip_runtime.h>
#include <math.h>

#define B_   128
#define R_   1152
#define RS_  64
#define RCH_ 18            // R_/RS_
#define NBINS 72           // 1152/16 colsum bins

// ws float offsets
#define WS_SP   0          // RS_*32768 = 2097152
#define WS_V    2097152    // 32768
#define WS_BLOG 2129920    // 18432
#define WS_CTRL 2148352    // 2560 floats: cs0 bins @+0 (72*16), cs1 bins @+1280
#define WS_WT   2150912    // 2359296 (Wt4[r*512 + d*64 + co4])

__device__ __forceinline__ float squashf(float s) {
    return s * fabsf(s) / (1.0f + s * s);
}

// ---------- T: Wt4[r*512 + d*64 + co4] = W4[r*512 + co4*8 + d]  (pitch-65 LDS swizzle)
//             + zero the colsum bin area once per run
__global__ __launch_bounds__(512) void wtrans_k(const float* __restrict__ W,
                                                float* __restrict__ wt,
                                                float* __restrict__ ctrl) {
    const int r = blockIdx.x;
    const int t = threadIdx.x;
    __shared__ float4 sh[520];
    const float4* __restrict__ W4 = (const float4*)W;
    float4* __restrict__ Wt4 = (float4*)wt;

    if (r == 0) {
        for (int u = t; u < 2560; u += 512) ctrl[u] = 0.0f;
    }

    sh[(t & 7) * 65 + (t >> 3)] = W4[r * 512 + t];     // t = co4*8 + d
    __syncthreads();
    Wt4[r * 512 + t] = sh[(t >> 6) * 65 + (t & 63)];   // t = d*64 + co4
}

// ---------- G: sp[rs][b][co] = sum_{r in chunk,i} x[b,r,i]*cw[r,c]*W[r,co,i]
// grid dim3(16 bt, RS_ rs) x 256 — R6 body with 2x finer batch split:
// 1024 blocks = 4 blocks/CU = 16 waves/CU for L2-latency hiding.
// FIRST: cw = 1/R exactly. Else cw = exp(blog)*1/colsum from 72x16 bins.
template <bool FIRST>
__global__ __launch_bounds__(256) void gemm_s_k(const float* __restrict__ x,
                                                const float* __restrict__ wt,
                                                const float* __restrict__ blog,
                                                const float* __restrict__ colbins,
                                                float* __restrict__ sp) {
    const int bt  = blockIdx.x;           // 0..15 (8 b each)
    const int rs  = blockIdx.y;
    const int t   = threadIdx.x;
    const int co4 = t & 63;
    const int b4  = t >> 6;               // 0..3 (2 b each)
    const int c   = co4 >> 2;
    const int r0  = rs * RCH_;

    __shared__ float4 xl4[288];         // 8 b x 18 r x 2 f4 = 4.6 KB
    __shared__ float  cwl[RCH_ * 16];   // 288
    __shared__ float  colinv_sh[16];
    __shared__ float  psum[256];

    const float4* __restrict__ X4  = (const float4*)x;
    const float4* __restrict__ Wt4 = (const float4*)wt;

    // stage x tile: 8 b x 18 r x 2 f4
    #pragma unroll
    for (int k = 0; k < 2; ++k) {
        const int u = t + k * 256;
        if (u < 288) {
            const int bl = u / 36, rem = u % 36;
            xl4[u] = X4[((bt * 8 + bl) * R_ + r0) * 2 + rem];
        }
    }

    // prepass: colinv from bins (16 j-lanes x 16 cc), then cwl rows
    if (!FIRST) {
        const int cc = t & 15, jb = t >> 4;
        float s = 0.f;
        for (int j = jb; j < NBINS; j += 16) s += colbins[j * 16 + cc];
        psum[t] = s;
        __syncthreads();
        if (t < 16) {
            float tot = 0.f;
            #pragma unroll
            for (int k2 = 0; k2 < 16; ++k2) tot += psum[k2 * 16 + t];
            colinv_sh[t] = 1.0f / tot;
        }
        __syncthreads();
        for (int u2 = t; u2 < RCH_ * 16; u2 += 256) {
            const int rl = u2 >> 4, c2 = u2 & 15;
            cwl[u2] = __expf(blog[(r0 + rl) * 16 + c2]) * colinv_sh[c2];
        }
    }
    __syncthreads();

    float acc[2][4];
    #pragma unroll
    for (int j = 0; j < 2; ++j)
        #pragma unroll
        for (int q = 0; q < 4; ++q) acc[j][q] = 0.f;

    // R6-identical hot loop structure (named w0..w7, unroll 3), j-extent 2
    #pragma unroll 3
    for (int rr = 0; rr < RCH_; ++rr) {
        const float cwv = FIRST ? (1.0f / (float)R_) : cwl[rr * 16 + c];
        const float4* wp = Wt4 + ((size_t)(r0 + rr) << 9) + co4;   // lane-stride 16B
        const float4 w0 = wp[  0], w1 = wp[ 64], w2 = wp[128], w3 = wp[192];
        const float4 w4 = wp[256], w5 = wp[320], w6 = wp[384], w7 = wp[448];
        #pragma unroll
        for (int j = 0; j < 2; ++j) {
            const float4 xa = xl4[(b4 * 2 + j) * 36 + rr * 2];
            const float4 xb = xl4[(b4 * 2 + j) * 36 + rr * 2 + 1];
            const float d0 = w0.x*xa.x + w0.y*xa.y + w0.z*xa.z + w0.w*xa.w
                           + w1.x*xb.x + w1.y*xb.y + w1.z*xb.z + w1.w*xb.w;
            const float d1 = w2.x*xa.x + w2.y*xa.y + w2.z*xa.z + w2.w*xa.w
                           + w3.x*xb.x + w3.y*xb.y + w3.z*xb.z + w3.w*xb.w;
            const float d2 = w4.x*xa.x + w4.y*xa.y + w4.z*xa.z + w4.w*xa.w
                           + w5.x*xb.x + w5.y*xb.y + w5.z*xb.z + w5.w*xb.w;
            const float d3 = w6.x*xa.x + w6.y*xa.y + w6.z*xa.z + w6.w*xa.w
                           + w7.x*xb.x + w7.y*xb.y + w7.z*xb.z + w7.w*xb.w;
            acc[j][0] = fmaf(cwv, d0, acc[j][0]);
            acc[j][1] = fmaf(cwv, d1, acc[j][1]);
            acc[j][2] = fmaf(cwv, d2, acc[j][2]);
            acc[j][3] = fmaf(cwv, d3, acc[j][3]);
        }
    }

    float4* sp4 = (float4*)sp;
    #pragma unroll
    for (int j = 0; j < 2; ++j) {
        const int b = bt * 8 + b4 * 2 + j;
        float4 o4; o4.x = acc[j][0]; o4.y = acc[j][1]; o4.z = acc[j][2]; o4.w = acc[j][3];
        sp4[(rs * B_ + b) * 64 + co4] = o4;
    }
}

// ---------- R: v[b,co] = squash(sum_k sp[k][b][co]); grid 256 x 512 (R6-identical)
__global__ __launch_bounds__(512) void reduce_squash_k(const float* __restrict__ sp,
                                                       float* __restrict__ outv) {
    const int t   = threadIdx.x;
    const int li  = t & 127;
    const int kq  = t >> 7;               // 0..3 (16 slices each)
    const int idx = blockIdx.x * 128 + li;
    const float* p = sp + (size_t)kq * 16 * 32768 + idx;
    float a0 = 0.f, a1 = 0.f, a2 = 0.f, a3 = 0.f;
    #pragma unroll
    for (int k = 0; k < 16; k += 4) {
        a0 += p[(k + 0) * 32768];
        a1 += p[(k + 1) * 32768];
        a2 += p[(k + 2) * 32768];
        a3 += p[(k + 3) * 32768];
    }
    __shared__ float red[512];
    red[t] = (a0 + a1) + (a2 + a3);
    __syncthreads();
    if (t < 128) {
        const float s = (red[t] + red[t + 128]) + (red[t + 256] + red[t + 384]);
        outv[idx] = squashf(s);
    }
}

// ---------- A: blog[r,c] (+)= (1/B) sum_{b,o} u_hat[b,r,co]*v[b,co] ----------
// R6-identical: grid 1152 x 256 (1 r/block; 4 waves = batch quarters),
// launch_bounds(256,2) keeps y[8][4] in registers; 72x16 colsum bins.
template <bool FIRST>
__global__ __launch_bounds__(256, 2) void a_k(const float* __restrict__ x,
                                              const float* __restrict__ wt,
                                              const float* __restrict__ v,
                                              float* __restrict__ blog,
                                              float* __restrict__ colbins) {
    const int r = blockIdx.x;
    const int t = threadIdx.x;
    const int w = t >> 6, lane = t & 63;
    const int co4 = lane, c = lane >> 2;

    __shared__ float4 xl[256];            // 128 b x 2 f4 = 4 KB
    __shared__ float  red[64];
    const float4* __restrict__ X4  = (const float4*)x;
    const float4* __restrict__ V4  = (const float4*)v;
    const float4* __restrict__ Wt4 = (const float4*)wt;

    xl[t] = X4[((t >> 1) * R_ + r) * 2 + (t & 1)];
    __syncthreads();

    float y[8][4];
    #pragma unroll
    for (int i = 0; i < 8; ++i)
        #pragma unroll
        for (int q = 0; q < 4; ++q) y[i][q] = 0.f;

    const int b0 = w * 32;
    #pragma unroll 4
    for (int bb = 0; bb < 32; ++bb) {
        const int b = b0 + bb;
        const float4 xa = xl[b * 2];
        const float4 xb = xl[b * 2 + 1];
        const float4 vv = V4[b * 64 + co4];
        y[0][0] = fmaf(xa.x, vv.x, y[0][0]); y[0][1] = fmaf(xa.x, vv.y, y[0][1]);
        y[0][2] = fmaf(xa.x, vv.z, y[0][2]); y[0][3] = fmaf(xa.x, vv.w, y[0][3]);
        y[1][0] = fmaf(xa.y, vv.x, y[1][0]); y[1][1] = fmaf(xa.y, vv.y, y[1][1]);
        y[1][2] = fmaf(xa.y, vv.z, y[1][2]); y[1][3] = fmaf(xa.y, vv.w, y[1][3]);
        y[2][0] = fmaf(xa.z, vv.x, y[2][0]); y[2][1] = fmaf(xa.z, vv.y, y[2][1]);
        y[2][2] = fmaf(xa.z, vv.z, y[2][2]); y[2][3] = fmaf(xa.z, vv.w, y[2][3]);
        y[3][0] = fmaf(xa.w, vv.x, y[3][0]); y[3][1] = fmaf(xa.w, vv.y, y[3][1]);
        y[3][2] = fmaf(xa.w, vv.z, y[3][2]); y[3][3] = fmaf(xa.w, vv.w, y[3][3]);
        y[4][0] = fmaf(xb.x, vv.x, y[4][0]); y[4][1] = fmaf(xb.x, vv.y, y[4][1]);
        y[4][2] = fmaf(xb.x, vv.z, y[4][2]); y[4][3] = fmaf(xb.x, vv.w, y[4][3]);
        y[5][0] = fmaf(xb.y, vv.x, y[5][0]); y[5][1] = fmaf(xb.y, vv.y, y[5][1]);
        y[5][2] = fmaf(xb.y, vv.z, y[5][2]); y[5][3] = fmaf(xb.y, vv.w, y[5][3]);
        y[6][0] = fmaf(xb.z, vv.x, y[6][0]); y[6][1] = fmaf(xb.z, vv.y, y[6][1]);
        y[6][2] = fmaf(xb.z, vv.z, y[6][2]); y[6][3] = fmaf(xb.z, vv.w, y[6][3]);
        y[7][0] = fmaf(xb.w, vv.x, y[7][0]); y[7][1] = fmaf(xb.w, vv.y, y[7][1]);
        y[7][2] = fmaf(xb.w, vv.z, y[7][2]); y[7][3] = fmaf(xb.w, vv.w, y[7][3]);
    }

    const float4* wp = Wt4 + ((size_t)r << 9) + co4;
    float part = 0.f;
    #pragma unroll
    for (int q = 0; q < 4; ++q) {
        const float4 w0 = wp[(2 * q) * 64];
        const float4 w1 = wp[(2 * q + 1) * 64];
        part += w0.x*y[0][q] + w0.y*y[1][q] + w0.z*y[2][q] + w0.w*y[3][q]
              + w1.x*y[4][q] + w1.y*y[5][q] + w1.z*y[6][q] + w1.w*y[7][q];
    }
    part += __shfl_xor(part, 1);
    part += __shfl_xor(part, 2);
    if ((lane & 3) == 0) red[w * 16 + c] = part;
    __syncthreads();
    if (t < 16) {
        const float val = ((red[t] + red[16 + t]) + (red[32 + t] + red[48 + t]))
                          * (1.0f / (float)B_);
        const int idx = r * 16 + t;
        const float nv = FIRST ? val : (blog[idx] + val);
        blog[idx] = nv;
        atomicAdd(&colbins[(r >> 4) * 16 + t], __expf(nv));  // 16-deep chains
    }
}

extern "C" void kernel_launch(void* const* d_in, const int* in_sizes, int n_in,
                              void* d_out, int out_size, void* d_ws, size_t ws_size,
                              hipStream_t stream) {
    const float* x = (const float*)d_in[0];   // [128,1152,8]
    const float* W = (const float*)d_in[1];   // [1,1152,16,16,8]
    float* out = (float*)d_out;               // [128,16,16]
    float* ws  = (float*)d_ws;                // ~18 MB used

    float* sp   = ws + WS_SP;
    float* v    = ws + WS_V;
    float* blog = ws + WS_BLOG;
    float* ctrl = ws + WS_CTRL;
    float* wt   = ws + WS_WT;

    float* cs0 = ctrl;                        // 72x16 bins
    float* cs1 = ctrl + 1280;                 // 72x16 bins

    // build Wt once (coalesced transpose) + zero colsum bins
    wtrans_k<<<R_, 512, 0, stream>>>(W, wt, ctrl);

    // iter 0 (softmax(0) == 1/R exactly)
    gemm_s_k<true ><<<dim3(16, RS_), 256, 0, stream>>>(x, wt, nullptr, nullptr, sp);
    reduce_squash_k<<<256, 512, 0, stream>>>(sp, v);
    a_k<true ><<<R_, 256, 0, stream>>>(x, wt, v, blog, cs0);

    // iter 1
    gemm_s_k<false><<<dim3(16, RS_), 256, 0, stream>>>(x, wt, blog, cs0, sp);
    reduce_squash_k<<<256, 512, 0, stream>>>(sp, v);
    a_k<false><<<R_, 256, 0, stream>>>(x, wt, v, blog, cs1);

    // iter 2
    gemm_s_k<false><<<dim3(16, RS_), 256, 0, stream>>>(x, wt, blog, cs1, sp);
    reduce_squash_k<<<256, 512, 0, stream>>>(sp, out);
}